// Round 7
// baseline (158.757 us; speedup 1.0000x reference)
//
#include <hip/hip_runtime.h>
#include <hip/hip_bf16.h>

#define SEQ    2048
#define DMODEL 1024
#define HEADS  16
#define DHEAD  64
#define BATCH  2
#define TOK    (BATCH * SEQ)    // 4096
#define NQKV   (3 * DMODEL)     // 3072
#define QK_SCALE (0.125f * 1.4426950408889634f)   // fold DH^-0.5 and log2(e) into q

typedef __attribute__((ext_vector_type(8))) short bf16x8;
typedef __attribute__((ext_vector_type(4))) float f32x4;

__device__ __forceinline__ float bf2f(ushort u) {
  union { unsigned int i; float f; } v; v.i = ((unsigned int)u) << 16; return v.f;
}
__device__ __forceinline__ ushort f2bf(float f) {
  union { float f; unsigned int i; } v; v.f = f;
  unsigned int r = (v.i + 0x7fffu + ((v.i >> 16) & 1u)) >> 16;
  return (ushort)r;
}

// XOR-swizzle for [row][128-byte-row] LDS tiles (attn): spreads 16B slots across banks.
__device__ __forceinline__ int swz(int row, int byteoff) {
  return row * 128 + (byteoff ^ ((row & 7) << 4));
}
// K-row permutation (attn): LDS slot s = nf*16+g*4+r holds global kv row
// pi(s) = nf1*32 + g*8 + nf0*4 + r  -> lane (g) ends up holding exactly kv
// {g*8..g*8+7} u {32+g*8..+7}: the PV A-fragment, with no cross-lane traffic.
__device__ __forceinline__ int kperm(int s) {
  return (s & 0x20) | ((s & 0x0C) << 1) | ((s & 0x10) >> 2) | (s & 3);
}

#define GLL16(g, l)                                                                     \
  __builtin_amdgcn_global_load_lds((const __attribute__((address_space(1))) void*)(g),  \
                                   (__attribute__((address_space(3))) void*)(l), 16, 0, 0)

// ---------------- LayerNorm: fp32 in -> bf16 out, one block per token ----------------
__global__ __launch_bounds__(256) void ln_kernel(const float* __restrict__ x,
                                                 const float* __restrict__ g,
                                                 const float* __restrict__ b,
                                                 ushort* __restrict__ xn) {
  int t = blockIdx.x;
  int tid = threadIdx.x;
  const float* row = x + (size_t)t * DMODEL;
  float4 v = *(const float4*)(row + tid * 4);
  float s  = v.x + v.y + v.z + v.w;
  float s2 = v.x * v.x + v.y * v.y + v.z * v.z + v.w * v.w;
#pragma unroll
  for (int m = 32; m >= 1; m >>= 1) {
    s  += __shfl_down(s, m);
    s2 += __shfl_down(s2, m);
  }
  __shared__ float ws[4], ws2[4];
  if ((tid & 63) == 0) { ws[tid >> 6] = s; ws2[tid >> 6] = s2; }
  __syncthreads();
  s  = ws[0] + ws[1] + ws[2] + ws[3];
  s2 = ws2[0] + ws2[1] + ws2[2] + ws2[3];
  float mu  = s * (1.f / DMODEL);
  float var = s2 * (1.f / DMODEL) - mu * mu;
  float rs  = rsqrtf(var + 1e-5f);
  float4 gv = *(const float4*)(g + tid * 4);
  float4 bv = *(const float4*)(b + tid * 4);
  ushort4 o;
  o.x = f2bf((v.x - mu) * rs * gv.x + bv.x);
  o.y = f2bf((v.y - mu) * rs * gv.y + bv.y);
  o.z = f2bf((v.z - mu) * rs * gv.z + bv.z);
  o.w = f2bf((v.w - mu) * rs * gv.w + bv.w);
  *(ushort4*)(xn + (size_t)t * DMODEL + tid * 4) = o;
}

// ---------------- fp32 [R][C] -> bf16 [C][R] transpose ----------------
__global__ void transpose_f2b(const float* __restrict__ in, ushort* __restrict__ out,
                              int R, int C) {
  __shared__ float tile[32][33];
  int c0 = blockIdx.x * 32, r0 = blockIdx.y * 32;
  int x = threadIdx.x, y = threadIdx.y;
#pragma unroll
  for (int i = 0; i < 32; i += 8) tile[y + i][x] = in[(size_t)(r0 + y + i) * C + c0 + x];
  __syncthreads();
#pragma unroll
  for (int i = 0; i < 32; i += 8) out[(size_t)(c0 + y + i) * R + r0 + x] = f2bf(tile[x][y + i]);
}

// ---------------- RoPE cos/sin tables [SEQ][DHEAD] fp32 ----------------
__global__ void rope_tab_kernel(float* __restrict__ ct, float* __restrict__ st) {
  int n = blockIdx.x, d = threadIdx.x;
  float invf = expf(-logf(10000.f) * (float)(d & 31) * (1.f / 32.f));
  float a = (float)n * invf;
  ct[n * DHEAD + d] = cosf(a);
  st[n * DHEAD + d] = sinf(a);
}

// ---- GEMM: C[M][N] = A[M][K] * BT[N][K]^T; bf16 in. BK=32, double-buffered 32KB LDS.
// T3-minimum schedule: stage tile t+1 BEFORE computing tile t; one barrier per
// K-step; global loads fly under ds_read+MFMA. Slot-XOR swizzle (free T2) kept:
// LDS (row, slot) holds global (row, slot ^ ((row>>1)&3)); source pre-swizzled
// (gll16 dest linear, rule #21), fragment read XORs the same involution.
// EPI==1: RoPE + head-scatter epilogue (QKV GEMM) -> qh/kh/vh, q pre-scaled for exp2.
// EPI==2: fp32 + bias -> Cf (output projection).
template<int EPI>
__global__ __launch_bounds__(256) void gemm_bt(const ushort* __restrict__ A,
                                               const ushort* __restrict__ BT,
                                               float* __restrict__ Cf,
                                               const float* __restrict__ bias,
                                               ushort* __restrict__ qh,
                                               ushort* __restrict__ kh,
                                               ushort* __restrict__ vh,
                                               const float* __restrict__ ct,
                                               const float* __restrict__ st,
                                               int M, int N, int K) {
  __shared__ __align__(16) ushort As[2][128 * 32];
  __shared__ __align__(16) ushort Bs[2][128 * 32];
  int tid = threadIdx.x;
  int w = tid >> 6, lane = tid & 63;
  int lrow = lane & 15, g = lane >> 4;
  int m0 = blockIdx.y * 128, n0 = blockIdx.x * 128;
  int wr = (w >> 1) * 64, wc = (w & 1) * 64;
  // staging: lane covers row (lane>>2) of a 16-row chunk, slot lane&3; source col
  // pre-swizzled with the involution slot ^= (row>>1)&3.
  int grow = lane >> 2;
  int gcol = ((lane & 3) ^ ((grow >> 1) & 3)) * 8;
  // fragment read: logical slot g lives at LDS slot g ^ ((row>>1)&3); row bits 1,2
  // within a 16-row fragment come from lrow only.
  int fcol = (g ^ ((lrow >> 1) & 3)) * 8;
  const ushort* arow0 = A  + (size_t)(m0 + w * 16 + grow) * K + gcol;
  const ushort* arow1 = A  + (size_t)(m0 + 64 + w * 16 + grow) * K + gcol;
  const ushort* brow0 = BT + (size_t)(n0 + w * 16 + grow) * K + gcol;
  const ushort* brow1 = BT + (size_t)(n0 + 64 + w * 16 + grow) * K + gcol;
  f32x4 acc[4][4] = {};

#define GSTAGE(bsel, k0)                              \
  {                                                   \
    GLL16(arow0 + (k0), As[bsel] + w * 512);          \
    GLL16(arow1 + (k0), As[bsel] + 2048 + w * 512);   \
    GLL16(brow0 + (k0), Bs[bsel] + w * 512);          \
    GLL16(brow1 + (k0), Bs[bsel] + 2048 + w * 512);   \
  }

#define GCOMPUTE(bsel)                                                                     \
  {                                                                                        \
    bf16x8 af[4], bfr[4];                                                                  \
    _Pragma("unroll")                                                                      \
    for (int i = 0; i < 4; i++) af[i]  = *(const bf16x8*)(As[bsel] + (wr + i * 16 + lrow) * 32 + fcol); \
    _Pragma("unroll")                                                                      \
    for (int i = 0; i < 4; i++) bfr[i] = *(const bf16x8*)(Bs[bsel] + (wc + i * 16 + lrow) * 32 + fcol); \
    __builtin_amdgcn_s_setprio(1);                                                         \
    _Pragma("unroll")                                                                      \
    for (int mf = 0; mf < 4; mf++)                                                         \
      _Pragma("unroll")                                                                    \
      for (int nf = 0; nf < 4; nf++)                                                       \
        acc[mf][nf] = __builtin_amdgcn_mfma_f32_16x16x32_bf16(af[mf], bfr[nf], acc[mf][nf], 0, 0, 0); \
    __builtin_amdgcn_s_setprio(0);                                                         \
  }

  int nk = K >> 5;                 // K-steps of 32 (nk is even for K=1024)
  GSTAGE(0, 0);
  __syncthreads();                 // buf0 ready
  for (int t = 0; t < nk; t += 2) {
    if (t + 1 < nk) GSTAGE(1, (t + 1) << 5);   // loads fly under compute of buf0
    GCOMPUTE(0);
    __syncthreads();               // drains buf1 loads; all waves done reading buf0
    if (t + 2 < nk) GSTAGE(0, (t + 2) << 5);
    GCOMPUTE(1);
    __syncthreads();
  }
#undef GSTAGE
#undef GCOMPUTE

#pragma unroll
  for (int mf = 0; mf < 4; mf++)
#pragma unroll
    for (int nf = 0; nf < 4; nf++) {
      int col = n0 + wc + nf * 16 + lrow;
#pragma unroll
      for (int r = 0; r < 4; r++) {
        int rowi = m0 + wr + mf * 16 + g * 4 + r;   // C/D: col=lane&15, row=4*(lane>>4)+reg
        float val = acc[mf][nf][r];
        if (EPI == 2) {
          Cf[(size_t)rowi * N + col] = val + bias[col];
        } else {
          int mat = col >> 10, c1 = col & 1023;
          int h = c1 >> 6, d = c1 & 63;
          int bb = rowi >> 11, n = rowi & (SEQ - 1);
          if (mat < 2) {
            float partner = acc[mf][nf ^ 2][r];     // col ^ 32 lives in the same lane
            float cs = ct[n * DHEAD + d], sn = st[n * DHEAD + d];
            float sgn = (d & 32) ? 1.f : -1.f;
            val = val * cs + sgn * partner * sn;
            if (mat == 0) val *= QK_SCALE;
          }
          ushort* dst = (mat == 0) ? qh : (mat == 1) ? kh : vh;
          dst[((size_t)(bb * HEADS + h) * SEQ + n) * DHEAD + d] = f2bf(val);
        }
      }
    }
}

// ---------------- causal flash attention ----------------
// Block = (pair of q-tiles {pid, 31-pid}, head): uniform work, shared K/V staging.
// Swapped QK^T (mfma(K,Q) -> S^T) + kperm'd K rows => each lane holds exactly its
// PV A-fragment scores: softmax is lane-local, no P LDS round-trip, no shuffles.
__global__ __launch_bounds__(256) void attn_kernel(const ushort* __restrict__ q,
                                                   const ushort* __restrict__ k,
                                                   const ushort* __restrict__ v,
                                                   ushort* __restrict__ ao) {
  int wgid = blockIdx.x + gridDim.x * blockIdx.y;   // 0..511
  int j5 = wgid >> 3;
  int bh  = (wgid & 7) * 4 + (j5 >> 4);   // 4 heads per XCD: K+V (2MB) fits L2
  int pid = j5 & 15;
  int qlo = pid, qhi = (SEQ / 64 - 1) - pid;
  int tid = threadIdx.x, w = tid >> 6, lane = tid & 63;
  int lrow = lane & 15, g = lane >> 4;
  __shared__ __align__(16) ushort Ks[2][64 * 64];
  __shared__ __align__(16) ushort Vt[2][64 * 64];
  const ushort* qb = q + (size_t)bh * SEQ * DHEAD;
  const ushort* kb = k + (size_t)bh * SEQ * DHEAD;
  const ushort* vb = v + (size_t)bh * SEQ * DHEAD;
  const ushort* qph = qb + (size_t)(qhi * 64 + w * 16 + lrow) * DHEAD + g * 8;
  const ushort* qpl = qb + (size_t)(qlo * 64 + w * 16 + lrow) * DHEAD + g * 8;
  bf16x8 qh0 = *(const bf16x8*)(qph), qh1 = *(const bf16x8*)(qph + 32);
  bf16x8 ql0 = *(const bf16x8*)(qpl), ql1 = *(const bf16x8*)(qpl + 32);
  f32x4 aOh[4] = {}, aOl[4] = {};
  float l_hi = 0.f, l_lo = 0.f;

  int krow = tid >> 2, kco = (tid & 3) * 16;
  int pik = kperm(krow);
  int d0 = (tid & 31) * 2, kv8 = (tid >> 5) * 8;
  int4 ka0, ka1;
  unsigned int vd[8];

#define STAGE_ISSUE(j)                                                          \
  {                                                                             \
    const ushort* ks = kb + ((size_t)((j) * 64 + pik)) * DHEAD + kco;           \
    ka0 = *(const int4*)ks;                                                     \
    ka1 = *(const int4*)(ks + 8);                                               \
    const ushort* vs = vb + ((size_t)((j) * 64 + kv8)) * DHEAD + d0;            \
    _Pragma("unroll")                                                           \
    for (int jj = 0; jj < 8; jj++) vd[jj] = *(const unsigned int*)(vs + jj * DHEAD); \
  }

#define STAGE_WRITE(bsel)                                                       \
  {                                                                             \
    char* kd = (char*)Ks[bsel];                                                 \
    *(int4*)(kd + swz(krow, (tid & 3) * 32)) = ka0;                             \
    *(int4*)(kd + swz(krow, (tid & 3) * 32 + 16)) = ka1;                        \
    unsigned int lo[4], hi[4];                                                  \
    _Pragma("unroll")                                                           \
    for (int jj = 0; jj < 4; jj++) {                                            \
      lo[jj] = __builtin_amdgcn_perm(vd[2 * jj + 1], vd[2 * jj], 0x05040100u);  \
      hi[jj] = __builtin_amdgcn_perm(vd[2 * jj + 1], vd[2 * jj], 0x07060302u);  \
    }                                                                           \
    char* vdst = (char*)Vt[bsel];                                               \
    *(int4*)(vdst + swz(d0, kv8 * 2))     = *(int4*)lo;                         \
    *(int4*)(vdst + swz(d0 + 1, kv8 * 2)) = *(int4*)hi;                         \
  }

  STAGE_ISSUE(0);
  STAGE_WRITE(0);
  __syncthreads();
  int cur = 0;

  for (int jt = 0; jt <= qhi; jt++) {
    if (jt < qhi) STAGE_ISSUE(jt + 1);
    const char* kbuf = (const char*)Ks[cur];
    const char* vbuf = (const char*)Vt[cur];
    bf16x8 kf[8];
#pragma unroll
    for (int nf = 0; nf < 4; nf++) {
      kf[2 * nf]     = *(const bf16x8*)(kbuf + swz(nf * 16 + lrow, g * 16));
      kf[2 * nf + 1] = *(const bf16x8*)(kbuf + swz(nf * 16 + lrow, g * 16 + 64));
    }
    // ---- hi tile: S^T = K.Q^T ; scores for q-row (w*16+lrow) land lane-local
    bf16x8 pah0, pah1, pal0, pal1;
    bool do_lo = (jt <= qlo);
    {
      f32x4 aS[4] = {};
      __builtin_amdgcn_s_setprio(1);
#pragma unroll
      for (int nf = 0; nf < 4; nf++) {
        aS[nf] = __builtin_amdgcn_mfma_f32_16x16x32_bf16(kf[2 * nf], qh0, aS[nf], 0, 0, 0);
        aS[nf] = __builtin_amdgcn_mfma_f32_16x16x32_bf16(kf[2 * nf + 1], qh1, aS[nf], 0, 0, 0);
      }
      __builtin_amdgcn_s_setprio(0);
      union { bf16x8 v; __hip_bfloat162 h[4]; } a0, a1;
      bool diag = (jt == qhi);
#pragma unroll
      for (int nf = 0; nf < 4; nf++) {
        float p[4];
#pragma unroll
        for (int r = 0; r < 4; r++) {
          int kvl = (nf >> 1) * 32 + g * 8 + (nf & 1) * 4 + r;
          p[r] = exp2f(aS[nf][r]);
          if (diag && kvl > w * 16 + lrow) p[r] = 0.f;
          l_hi += p[r];
        }
        __hip_bfloat162 plo = __float22bfloat162_rn({p[0], p[1]});
        __hip_bfloat162 phi = __float22bfloat162_rn({p[2], p[3]});
        if (nf < 2) { a0.h[(nf & 1) * 2] = plo; a0.h[(nf & 1) * 2 + 1] = phi; }
        else        { a1.h[(nf & 1) * 2] = plo; a1.h[(nf & 1) * 2 + 1] = phi; }
      }
      pah0 = a0.v; pah1 = a1.v;
    }
    if (do_lo) {
      f32x4 aS[4] = {};
      __builtin_amdgcn_s_setprio(1);
#pragma unroll
      for (int nf = 0; nf < 4; nf++) {
        aS[nf] = __builtin_amdgcn_mfma_f32_16x16x32_bf16(kf[2 * nf], ql0, aS[nf], 0, 0, 0);
        aS[nf] = __builtin_amdgcn_mfma_f32_16x16x32_bf16(kf[2 * nf + 1], ql1, aS[nf], 0, 0, 0);
      }
      __builtin_amdgcn_s_setprio(0);
      union { bf16x8 v; __hip_bfloat162 h[4]; } a0, a1;
      bool diag = (jt == qlo);
#pragma unroll
      for (int nf = 0; nf < 4; nf++) {
        float p[4];
#pragma unroll
        for (int r = 0; r < 4; r++) {
          int kvl = (nf >> 1) * 32 + g * 8 + (nf & 1) * 4 + r;
          p[r] = exp2f(aS[nf][r]);
          if (diag && kvl > w * 16 + lrow) p[r] = 0.f;
          l_lo += p[r];
        }
        __hip_bfloat162 plo = __float22bfloat162_rn({p[0], p[1]});
        __hip_bfloat162 phi = __float22bfloat162_rn({p[2], p[3]});
        if (nf < 2) { a0.h[(nf & 1) * 2] = plo; a0.h[(nf & 1) * 2 + 1] = phi; }
        else        { a1.h[(nf & 1) * 2] = plo; a1.h[(nf & 1) * 2 + 1] = phi; }
      }
      pal0 = a0.v; pal1 = a1.v;
    }
    bf16x8 vf[8];
#pragma unroll
    for (int nf = 0; nf < 4; nf++) {
      vf[2 * nf]     = *(const bf16x8*)(vbuf + swz(nf * 16 + lrow, g * 16));
      vf[2 * nf + 1] = *(const bf16x8*)(vbuf + swz(nf * 16 + lrow, g * 16 + 64));
    }
    __builtin_amdgcn_s_setprio(1);
#pragma unroll
    for (int nf = 0; nf < 4; nf++) {
      aOh[nf] = __builtin_amdgcn_mfma_f32_16x16x32_bf16(pah0, vf[2 * nf], aOh[nf], 0, 0, 0);
      aOh[nf] = __builtin_amdgcn_mfma_f32_16x16x32_bf16(pah1, vf[2 * nf + 1], aOh[nf], 0, 0, 0);
    }
    if (do_lo) {
#pragma unroll
      for (int nf = 0; nf < 4; nf++) {
        aOl[nf] = __builtin_amdgcn_mfma_f32_16x16x32_bf16(pal0, vf[2 * nf], aOl[nf], 0, 0, 0);
        aOl[nf] = __builtin_amdgcn_mfma_f32_16x16x32_bf16(pal1, vf[2 * nf + 1], aOl[nf], 0, 0, 0);
      }
    }
    __builtin_amdgcn_s_setprio(0);
    if (jt < qhi) STAGE_WRITE(cur ^ 1);
    __syncthreads();
    cur ^= 1;
  }

  // reduce denominators across the 4 lanes sharing each q-row, then write out
  l_hi += __shfl_xor(l_hi, 16); l_hi += __shfl_xor(l_hi, 32);
  l_lo += __shfl_xor(l_lo, 16); l_lo += __shfl_xor(l_lo, 32);
  int b = bh >> 4, h = bh & 15;
#pragma unroll
  for (int r = 0; r < 4; r++) {
    float ih = 1.f / __shfl(l_hi, g * 4 + r);
    float il = 1.f / __shfl(l_lo, g * 4 + r);
#pragma unroll
    for (int nf = 0; nf < 4; nf++) {
      int col = h * DHEAD + nf * 16 + lrow;
      int th = b * SEQ + qhi * 64 + w * 16 + g * 4 + r;
      int tl = b * SEQ + qlo * 64 + w * 16 + g * 4 + r;
      ao[(size_t)th * DMODEL + col] = f2bf(aOh[nf][r] * ih);
      ao[(size_t)tl * DMODEL + col] = f2bf(aOl[nf][r] * il);
    }
  }
#undef STAGE_ISSUE
#undef STAGE_WRITE
}

extern "C" void kernel_launch(void* const* d_in, const int* in_sizes, int n_in,
                              void* d_out, int out_size, void* d_ws, size_t ws_size,
                              hipStream_t stream) {
  const float* x    = (const float*)d_in[0];
  const float* Wqkv = (const float*)d_in[1];
  const float* Wout = (const float*)d_in[2];
  const float* bout = (const float*)d_in[3];
  const float* lng  = (const float*)d_in[4];
  const float* lnb  = (const float*)d_in[5];
  float* out = (float*)d_out;

  ushort* xn    = (ushort*)d_ws;                       // reused as ao after QKV GEMM
  ushort* WqkvT = xn + (size_t)TOK * DMODEL;
  ushort* WoutT = WqkvT + (size_t)NQKV * DMODEL;
  ushort* qh    = WoutT + (size_t)DMODEL * DMODEL;
  ushort* kh    = qh + (size_t)BATCH * HEADS * SEQ * DHEAD;
  ushort* vh    = kh + (size_t)BATCH * HEADS * SEQ * DHEAD;
  float*  ct    = (float*)(vh + (size_t)BATCH * HEADS * SEQ * DHEAD);
  float*  st    = ct + SEQ * DHEAD;
  ushort* ao    = xn;

  hipLaunchKernelGGL(ln_kernel, dim3(TOK), dim3(256), 0, stream, x, lng, lnb, xn);
  hipLaunchKernelGGL(transpose_f2b, dim3(NQKV / 32, DMODEL / 32), dim3(32, 8), 0, stream,
                     Wqkv, WqkvT, DMODEL, NQKV);
  hipLaunchKernelGGL(transpose_f2b, dim3(DMODEL / 32, DMODEL / 32), dim3(32, 8), 0, stream,
                     Wout, WoutT, DMODEL, DMODEL);
  hipLaunchKernelGGL(rope_tab_kernel, dim3(SEQ), dim3(DHEAD), 0, stream, ct, st);
  hipLaunchKernelGGL(gemm_bt<1>, dim3(NQKV / 128, TOK / 128), dim3(256), 0, stream,
                     xn, WqkvT, (float*)nullptr, (const float*)nullptr,
                     qh, kh, vh, ct, st, TOK, NQKV, DMODEL);
  hipLaunchKernelGGL(attn_kernel, dim3(16, BATCH * HEADS), dim3(256), 0, stream,
                     qh, kh, vh, ao);
  hipLaunchKernelGGL(gemm_bt<2>, dim3(DMODEL / 128, TOK / 128), dim3(256), 0, stream,
                     ao, WoutT, out, bout,
                     (ushort*)nullptr, (ushort*)nullptr, (ushort*)nullptr,
                     (const float*)nullptr, (const float*)nullptr, TOK, DMODEL, DMODEL);
}

// Round 8
// 136.244 us; speedup vs baseline: 1.1652x; 1.1652x over previous
//
#include <hip/hip_runtime.h>
#include <hip/hip_bf16.h>

#define SEQ    2048
#define DMODEL 1024
#define HEADS  16
#define DHEAD  64
#define BATCH  2
#define TOK    (BATCH * SEQ)    // 4096
#define NQKV   (3 * DMODEL)     // 3072
#define QK_SCALE (0.125f * 1.4426950408889634f)   // fold DH^-0.5 and log2(e) into q

typedef __attribute__((ext_vector_type(8))) short bf16x8;
typedef __attribute__((ext_vector_type(4))) float f32x4;

__device__ __forceinline__ float bf2f(ushort u) {
  union { unsigned int i; float f; } v; v.i = ((unsigned int)u) << 16; return v.f;
}
__device__ __forceinline__ ushort f2bf(float f) {
  union { float f; unsigned int i; } v; v.f = f;
  unsigned int r = (v.i + 0x7fffu + ((v.i >> 16) & 1u)) >> 16;
  return (ushort)r;
}

// XOR-swizzle for [row][128-byte-row] LDS tiles (attn): spreads 16B slots across banks.
__device__ __forceinline__ int swz(int row, int byteoff) {
  return row * 128 + (byteoff ^ ((row & 7) << 4));
}
// K-row permutation (attn): LDS slot s = nf*16+g*4+r holds global kv row
// pi(s) = nf1*32 + g*8 + nf0*4 + r  -> lane (g) ends up holding exactly kv
// {g*8..g*8+7} u {32+g*8..+7}: the PV A-fragment, with no cross-lane traffic.
__device__ __forceinline__ int kperm(int s) {
  return (s & 0x20) | ((s & 0x0C) << 1) | ((s & 0x10) >> 2) | (s & 3);
}

#define GLL16(g, l)                                                                     \
  __builtin_amdgcn_global_load_lds((const __attribute__((address_space(1))) void*)(g),  \
                                   (__attribute__((address_space(3))) void*)(l), 16, 0, 0)

// ---------------- LayerNorm: fp32 in -> bf16 out, one block per token ----------------
__global__ __launch_bounds__(256) void ln_kernel(const float* __restrict__ x,
                                                 const float* __restrict__ g,
                                                 const float* __restrict__ b,
                                                 ushort* __restrict__ xn) {
  int t = blockIdx.x;
  int tid = threadIdx.x;
  const float* row = x + (size_t)t * DMODEL;
  float4 v = *(const float4*)(row + tid * 4);
  float s  = v.x + v.y + v.z + v.w;
  float s2 = v.x * v.x + v.y * v.y + v.z * v.z + v.w * v.w;
#pragma unroll
  for (int m = 32; m >= 1; m >>= 1) {
    s  += __shfl_down(s, m);
    s2 += __shfl_down(s2, m);
  }
  __shared__ float ws[4], ws2[4];
  if ((tid & 63) == 0) { ws[tid >> 6] = s; ws2[tid >> 6] = s2; }
  __syncthreads();
  s  = ws[0] + ws[1] + ws[2] + ws[3];
  s2 = ws2[0] + ws2[1] + ws2[2] + ws2[3];
  float mu  = s * (1.f / DMODEL);
  float var = s2 * (1.f / DMODEL) - mu * mu;
  float rs  = rsqrtf(var + 1e-5f);
  float4 gv = *(const float4*)(g + tid * 4);
  float4 bv = *(const float4*)(b + tid * 4);
  ushort4 o;
  o.x = f2bf((v.x - mu) * rs * gv.x + bv.x);
  o.y = f2bf((v.y - mu) * rs * gv.y + bv.y);
  o.z = f2bf((v.z - mu) * rs * gv.z + bv.z);
  o.w = f2bf((v.w - mu) * rs * gv.w + bv.w);
  *(ushort4*)(xn + (size_t)t * DMODEL + tid * 4) = o;
}

// ---------------- fp32 [R][C] -> bf16 [C][R] transpose ----------------
__global__ void transpose_f2b(const float* __restrict__ in, ushort* __restrict__ out,
                              int R, int C) {
  __shared__ float tile[32][33];
  int c0 = blockIdx.x * 32, r0 = blockIdx.y * 32;
  int x = threadIdx.x, y = threadIdx.y;
#pragma unroll
  for (int i = 0; i < 32; i += 8) tile[y + i][x] = in[(size_t)(r0 + y + i) * C + c0 + x];
  __syncthreads();
#pragma unroll
  for (int i = 0; i < 32; i += 8) out[(size_t)(c0 + y + i) * R + r0 + x] = f2bf(tile[x][y + i]);
}

// ---------------- RoPE cos/sin tables [SEQ][DHEAD] fp32 ----------------
__global__ void rope_tab_kernel(float* __restrict__ ct, float* __restrict__ st) {
  int n = blockIdx.x, d = threadIdx.x;
  float invf = expf(-logf(10000.f) * (float)(d & 31) * (1.f / 32.f));
  float a = (float)n * invf;
  ct[n * DHEAD + d] = cosf(a);
  st[n * DHEAD + d] = sinf(a);
}

// ---- GEMM: C[M][N] = A[M][K] * BT[N][K]^T; bf16 in. BK=32, TRIPLE-buffered 48KB LDS.
// T4 counted-vmcnt schedule (m201/m218 mechanism): stage tile t+3 each iter; the
// pre-compute wait is vmcnt(8) — only tile t+1's 4 loads must land, 8 stay in
// flight across the barrier. Never vmcnt(0) in steady state. Raw s_barrier, not
// __syncthreads (which would drain everything — the rd7 failure). Slot-XOR T2
// swizzle kept (free): LDS (row, slot) = global (row, slot ^ ((row>>1)&3)).
// EPI==1: RoPE + head-scatter epilogue (QKV GEMM) -> qh/kh/vh, q pre-scaled for exp2.
// EPI==2: fp32 + bias -> Cf (output projection).
template<int EPI>
__global__ __launch_bounds__(256) void gemm_bt(const ushort* __restrict__ A,
                                               const ushort* __restrict__ BT,
                                               float* __restrict__ Cf,
                                               const float* __restrict__ bias,
                                               ushort* __restrict__ qh,
                                               ushort* __restrict__ kh,
                                               ushort* __restrict__ vh,
                                               const float* __restrict__ ct,
                                               const float* __restrict__ st,
                                               int M, int N, int K) {
  __shared__ __align__(16) ushort As[3][128 * 32];
  __shared__ __align__(16) ushort Bs[3][128 * 32];
  int tid = threadIdx.x;
  int w = tid >> 6, lane = tid & 63;
  int lrow = lane & 15, g = lane >> 4;
  int m0 = blockIdx.y * 128, n0 = blockIdx.x * 128;
  int wr = (w >> 1) * 64, wc = (w & 1) * 64;
  // staging: lane covers row (lane>>2) of a 16-row chunk, slot lane&3; source col
  // pre-swizzled with the involution slot ^= (row>>1)&3.
  int grow = lane >> 2;
  int gcol = ((lane & 3) ^ ((grow >> 1) & 3)) * 8;
  // fragment read: logical slot g lives at LDS slot g ^ ((row>>1)&3).
  int fcol = (g ^ ((lrow >> 1) & 3)) * 8;
  const ushort* arow0 = A  + (size_t)(m0 + w * 16 + grow) * K + gcol;
  const ushort* arow1 = A  + (size_t)(m0 + 64 + w * 16 + grow) * K + gcol;
  const ushort* brow0 = BT + (size_t)(n0 + w * 16 + grow) * K + gcol;
  const ushort* brow1 = BT + (size_t)(n0 + 64 + w * 16 + grow) * K + gcol;
  f32x4 acc[4][4] = {};

  ushort* pa0 = As[0]; ushort* pa1 = As[1]; ushort* pa2 = As[2];
  ushort* pb0 = Bs[0]; ushort* pb1 = Bs[1]; ushort* pb2 = Bs[2];

#define GSTAGE(pa, pb, k0)                        \
  {                                               \
    GLL16(arow0 + (k0), (pa) + w * 512);          \
    GLL16(arow1 + (k0), (pa) + 2048 + w * 512);   \
    GLL16(brow0 + (k0), (pb) + w * 512);          \
    GLL16(brow1 + (k0), (pb) + 2048 + w * 512);   \
  }

#define GCOMPUTE(pa, pb)                                                                   \
  {                                                                                        \
    bf16x8 af[4], bfr[4];                                                                  \
    _Pragma("unroll")                                                                      \
    for (int i = 0; i < 4; i++) af[i]  = *(const bf16x8*)((pa) + (wr + i * 16 + lrow) * 32 + fcol); \
    _Pragma("unroll")                                                                      \
    for (int i = 0; i < 4; i++) bfr[i] = *(const bf16x8*)((pb) + (wc + i * 16 + lrow) * 32 + fcol); \
    __builtin_amdgcn_s_setprio(1);                                                         \
    _Pragma("unroll")                                                                      \
    for (int mf = 0; mf < 4; mf++)                                                         \
      _Pragma("unroll")                                                                    \
      for (int nf = 0; nf < 4; nf++)                                                       \
        acc[mf][nf] = __builtin_amdgcn_mfma_f32_16x16x32_bf16(af[mf], bfr[nf], acc[mf][nf], 0, 0, 0); \
    __builtin_amdgcn_s_setprio(0);                                                         \
  }

  int nk = K >> 5;                       // 32 K-steps for K=1024
  GSTAGE(pa0, pb0, 0);
  GSTAGE(pa1, pb1, 32);
  GSTAGE(pa2, pb2, 64);
  asm volatile("s_waitcnt vmcnt(8)" ::: "memory");   // tile 0 landed; 8 in flight
  __builtin_amdgcn_s_barrier();
  __builtin_amdgcn_sched_barrier(0);

  for (int t = 0; t < nk; ++t) {
    GCOMPUTE(pa0, pb0);                  // consume tile t
    __builtin_amdgcn_s_barrier();        // all waves done reading buf before overwrite
    if (t + 3 < nk) {
      GSTAGE(pa0, pb0, (t + 3) << 5);    // refill cur buf with tile t+3
      asm volatile("s_waitcnt vmcnt(8)" ::: "memory");   // tile t+1 landed
    } else if (t + 2 < nk) {
      asm volatile("s_waitcnt vmcnt(4)" ::: "memory");
    } else {
      asm volatile("s_waitcnt vmcnt(0)" ::: "memory");
    }
    __builtin_amdgcn_s_barrier();        // all waves' t+1 loads visible
    __builtin_amdgcn_sched_barrier(0);
    ushort* ta = pa0; pa0 = pa1; pa1 = pa2; pa2 = ta;   // rotate buffers
    ushort* tb = pb0; pb0 = pb1; pb1 = pb2; pb2 = tb;
  }
#undef GSTAGE
#undef GCOMPUTE

#pragma unroll
  for (int mf = 0; mf < 4; mf++)
#pragma unroll
    for (int nf = 0; nf < 4; nf++) {
      int col = n0 + wc + nf * 16 + lrow;
#pragma unroll
      for (int r = 0; r < 4; r++) {
        int rowi = m0 + wr + mf * 16 + g * 4 + r;   // C/D: col=lane&15, row=4*(lane>>4)+reg
        float val = acc[mf][nf][r];
        if (EPI == 2) {
          Cf[(size_t)rowi * N + col] = val + bias[col];
        } else {
          int mat = col >> 10, c1 = col & 1023;
          int h = c1 >> 6, d = c1 & 63;
          int bb = rowi >> 11, n = rowi & (SEQ - 1);
          if (mat < 2) {
            float partner = acc[mf][nf ^ 2][r];     // col ^ 32 lives in the same lane
            float cs = ct[n * DHEAD + d], sn = st[n * DHEAD + d];
            float sgn = (d & 32) ? 1.f : -1.f;
            val = val * cs + sgn * partner * sn;
            if (mat == 0) val *= QK_SCALE;
          }
          ushort* dst = (mat == 0) ? qh : (mat == 1) ? kh : vh;
          dst[((size_t)(bb * HEADS + h) * SEQ + n) * DHEAD + d] = f2bf(val);
        }
      }
    }
}

// ---------------- causal flash attention ----------------
// Block = (pair of q-tiles {pid, 31-pid}, head): uniform work, shared K/V staging.
// Swapped QK^T (mfma(K,Q) -> S^T) + kperm'd K rows => each lane holds exactly its
// PV A-fragment scores: softmax is lane-local, no P LDS round-trip, no shuffles.
__global__ __launch_bounds__(256) void attn_kernel(const ushort* __restrict__ q,
                                                   const ushort* __restrict__ k,
                                                   const ushort* __restrict__ v,
                                                   ushort* __restrict__ ao) {
  int wgid = blockIdx.x + gridDim.x * blockIdx.y;   // 0..511
  int j5 = wgid >> 3;
  int bh  = (wgid & 7) * 4 + (j5 >> 4);   // 4 heads per XCD: K+V (2MB) fits L2
  int pid = j5 & 15;
  int qlo = pid, qhi = (SEQ / 64 - 1) - pid;
  int tid = threadIdx.x, w = tid >> 6, lane = tid & 63;
  int lrow = lane & 15, g = lane >> 4;
  __shared__ __align__(16) ushort Ks[2][64 * 64];
  __shared__ __align__(16) ushort Vt[2][64 * 64];
  const ushort* qb = q + (size_t)bh * SEQ * DHEAD;
  const ushort* kb = k + (size_t)bh * SEQ * DHEAD;
  const ushort* vb = v + (size_t)bh * SEQ * DHEAD;
  const ushort* qph = qb + (size_t)(qhi * 64 + w * 16 + lrow) * DHEAD + g * 8;
  const ushort* qpl = qb + (size_t)(qlo * 64 + w * 16 + lrow) * DHEAD + g * 8;
  bf16x8 qh0 = *(const bf16x8*)(qph), qh1 = *(const bf16x8*)(qph + 32);
  bf16x8 ql0 = *(const bf16x8*)(qpl), ql1 = *(const bf16x8*)(qpl + 32);
  f32x4 aOh[4] = {}, aOl[4] = {};
  float l_hi = 0.f, l_lo = 0.f;

  int krow = tid >> 2, kco = (tid & 3) * 16;
  int pik = kperm(krow);
  int d0 = (tid & 31) * 2, kv8 = (tid >> 5) * 8;
  int4 ka0, ka1;
  unsigned int vd[8];

#define STAGE_ISSUE(j)                                                          \
  {                                                                             \
    const ushort* ks = kb + ((size_t)((j) * 64 + pik)) * DHEAD + kco;           \
    ka0 = *(const int4*)ks;                                                     \
    ka1 = *(const int4*)(ks + 8);                                               \
    const ushort* vs = vb + ((size_t)((j) * 64 + kv8)) * DHEAD + d0;            \
    _Pragma("unroll")                                                           \
    for (int jj = 0; jj < 8; jj++) vd[jj] = *(const unsigned int*)(vs + jj * DHEAD); \
  }

#define STAGE_WRITE(bsel)                                                       \
  {                                                                             \
    char* kd = (char*)Ks[bsel];                                                 \
    *(int4*)(kd + swz(krow, (tid & 3) * 32)) = ka0;                             \
    *(int4*)(kd + swz(krow, (tid & 3) * 32 + 16)) = ka1;                        \
    unsigned int lo[4], hi[4];                                                  \
    _Pragma("unroll")                                                           \
    for (int jj = 0; jj < 4; jj++) {                                            \
      lo[jj] = __builtin_amdgcn_perm(vd[2 * jj + 1], vd[2 * jj], 0x05040100u);  \
      hi[jj] = __builtin_amdgcn_perm(vd[2 * jj + 1], vd[2 * jj], 0x07060302u);  \
    }                                                                           \
    char* vdst = (char*)Vt[bsel];                                               \
    *(int4*)(vdst + swz(d0, kv8 * 2))     = *(int4*)lo;                         \
    *(int4*)(vdst + swz(d0 + 1, kv8 * 2)) = *(int4*)hi;                         \
  }

  STAGE_ISSUE(0);
  STAGE_WRITE(0);
  __syncthreads();
  int cur = 0;

  for (int jt = 0; jt <= qhi; jt++) {
    if (jt < qhi) STAGE_ISSUE(jt + 1);
    const char* kbuf = (const char*)Ks[cur];
    const char* vbuf = (const char*)Vt[cur];
    bf16x8 kf[8];
#pragma unroll
    for (int nf = 0; nf < 4; nf++) {
      kf[2 * nf]     = *(const bf16x8*)(kbuf + swz(nf * 16 + lrow, g * 16));
      kf[2 * nf + 1] = *(const bf16x8*)(kbuf + swz(nf * 16 + lrow, g * 16 + 64));
    }
    // ---- hi tile: S^T = K.Q^T ; scores for q-row (w*16+lrow) land lane-local
    bf16x8 pah0, pah1, pal0, pal1;
    bool do_lo = (jt <= qlo);
    {
      f32x4 aS[4] = {};
      __builtin_amdgcn_s_setprio(1);
#pragma unroll
      for (int nf = 0; nf < 4; nf++) {
        aS[nf] = __builtin_amdgcn_mfma_f32_16x16x32_bf16(kf[2 * nf], qh0, aS[nf], 0, 0, 0);
        aS[nf] = __builtin_amdgcn_mfma_f32_16x16x32_bf16(kf[2 * nf + 1], qh1, aS[nf], 0, 0, 0);
      }
      __builtin_amdgcn_s_setprio(0);
      union { bf16x8 v; __hip_bfloat162 h[4]; } a0, a1;
      bool diag = (jt == qhi);
#pragma unroll
      for (int nf = 0; nf < 4; nf++) {
        float p[4];
#pragma unroll
        for (int r = 0; r < 4; r++) {
          int kvl = (nf >> 1) * 32 + g * 8 + (nf & 1) * 4 + r;
          p[r] = exp2f(aS[nf][r]);
          if (diag && kvl > w * 16 + lrow) p[r] = 0.f;
          l_hi += p[r];
        }
        __hip_bfloat162 plo = __float22bfloat162_rn({p[0], p[1]});
        __hip_bfloat162 phi = __float22bfloat162_rn({p[2], p[3]});
        if (nf < 2) { a0.h[(nf & 1) * 2] = plo; a0.h[(nf & 1) * 2 + 1] = phi; }
        else        { a1.h[(nf & 1) * 2] = plo; a1.h[(nf & 1) * 2 + 1] = phi; }
      }
      pah0 = a0.v; pah1 = a1.v;
    }
    if (do_lo) {
      f32x4 aS[4] = {};
      __builtin_amdgcn_s_setprio(1);
#pragma unroll
      for (int nf = 0; nf < 4; nf++) {
        aS[nf] = __builtin_amdgcn_mfma_f32_16x16x32_bf16(kf[2 * nf], ql0, aS[nf], 0, 0, 0);
        aS[nf] = __builtin_amdgcn_mfma_f32_16x16x32_bf16(kf[2 * nf + 1], ql1, aS[nf], 0, 0, 0);
      }
      __builtin_amdgcn_s_setprio(0);
      union { bf16x8 v; __hip_bfloat162 h[4]; } a0, a1;
      bool diag = (jt == qlo);
#pragma unroll
      for (int nf = 0; nf < 4; nf++) {
        float p[4];
#pragma unroll
        for (int r = 0; r < 4; r++) {
          int kvl = (nf >> 1) * 32 + g * 8 + (nf & 1) * 4 + r;
          p[r] = exp2f(aS[nf][r]);
          if (diag && kvl > w * 16 + lrow) p[r] = 0.f;
          l_lo += p[r];
        }
        __hip_bfloat162 plo = __float22bfloat162_rn({p[0], p[1]});
        __hip_bfloat162 phi = __float22bfloat162_rn({p[2], p[3]});
        if (nf < 2) { a0.h[(nf & 1) * 2] = plo; a0.h[(nf & 1) * 2 + 1] = phi; }
        else        { a1.h[(nf & 1) * 2] = plo; a1.h[(nf & 1) * 2 + 1] = phi; }
      }
      pal0 = a0.v; pal1 = a1.v;
    }
    bf16x8 vf[8];
#pragma unroll
    for (int nf = 0; nf < 4; nf++) {
      vf[2 * nf]     = *(const bf16x8*)(vbuf + swz(nf * 16 + lrow, g * 16));
      vf[2 * nf + 1] = *(const bf16x8*)(vbuf + swz(nf * 16 + lrow, g * 16 + 64));
    }
    __builtin_amdgcn_s_setprio(1);
#pragma unroll
    for (int nf = 0; nf < 4; nf++) {
      aOh[nf] = __builtin_amdgcn_mfma_f32_16x16x32_bf16(pah0, vf[2 * nf], aOh[nf], 0, 0, 0);
      aOh[nf] = __builtin_amdgcn_mfma_f32_16x16x32_bf16(pah1, vf[2 * nf + 1], aOh[nf], 0, 0, 0);
    }
    if (do_lo) {
#pragma unroll
      for (int nf = 0; nf < 4; nf++) {
        aOl[nf] = __builtin_amdgcn_mfma_f32_16x16x32_bf16(pal0, vf[2 * nf], aOl[nf], 0, 0, 0);
        aOl[nf] = __builtin_amdgcn_mfma_f32_16x16x32_bf16(pal1, vf[2 * nf + 1], aOl[nf], 0, 0, 0);
      }
    }
    __builtin_amdgcn_s_setprio(0);
    if (jt < qhi) STAGE_WRITE(cur ^ 1);
    __syncthreads();
    cur ^= 1;
  }

  // reduce denominators across the 4 lanes sharing each q-row, then write out
  l_hi += __shfl_xor(l_hi, 16); l_hi += __shfl_xor(l_hi, 32);
  l_lo += __shfl_xor(l_lo, 16); l_lo += __shfl_xor(l_lo, 32);
  int b = bh >> 4, h = bh & 15;
#pragma unroll
  for (int r = 0; r < 4; r++) {
    float ih = 1.f / __shfl(l_hi, g * 4 + r);
    float il = 1.f / __shfl(l_lo, g * 4 + r);
#pragma unroll
    for (int nf = 0; nf < 4; nf++) {
      int col = h * DHEAD + nf * 16 + lrow;
      int th = b * SEQ + qhi * 64 + w * 16 + g * 4 + r;
      int tl = b * SEQ + qlo * 64 + w * 16 + g * 4 + r;
      ao[(size_t)th * DMODEL + col] = f2bf(aOh[nf][r] * ih);
      ao[(size_t)tl * DMODEL + col] = f2bf(aOl[nf][r] * il);
    }
  }
#undef STAGE_ISSUE
#undef STAGE_WRITE
}

extern "C" void kernel_launch(void* const* d_in, const int* in_sizes, int n_in,
                              void* d_out, int out_size, void* d_ws, size_t ws_size,
                              hipStream_t stream) {
  const float* x    = (const float*)d_in[0];
  const float* Wqkv = (const float*)d_in[1];
  const float* Wout = (const float*)d_in[2];
  const float* bout = (const float*)d_in[3];
  const float* lng  = (const float*)d_in[4];
  const float* lnb  = (const float*)d_in[5];
  float* out = (float*)d_out;

  ushort* xn    = (ushort*)d_ws;                       // reused as ao after QKV GEMM
  ushort* WqkvT = xn + (size_t)TOK * DMODEL;
  ushort* WoutT = WqkvT + (size_t)NQKV * DMODEL;
  ushort* qh    = WoutT + (size_t)DMODEL * DMODEL;
  ushort* kh    = qh + (size_t)BATCH * HEADS * SEQ * DHEAD;
  ushort* vh    = kh + (size_t)BATCH * HEADS * SEQ * DHEAD;
  float*  ct    = (float*)(vh + (size_t)BATCH * HEADS * SEQ * DHEAD);
  float*  st    = ct + SEQ * DHEAD;
  ushort* ao    = xn;

  hipLaunchKernelGGL(ln_kernel, dim3(TOK), dim3(256), 0, stream, x, lng, lnb, xn);
  hipLaunchKernelGGL(transpose_f2b, dim3(NQKV / 32, DMODEL / 32), dim3(32, 8), 0, stream,
                     Wqkv, WqkvT, DMODEL, NQKV);
  hipLaunchKernelGGL(transpose_f2b, dim3(DMODEL / 32, DMODEL / 32), dim3(32, 8), 0, stream,
                     Wout, WoutT, DMODEL, DMODEL);
  hipLaunchKernelGGL(rope_tab_kernel, dim3(SEQ), dim3(DHEAD), 0, stream, ct, st);
  hipLaunchKernelGGL(gemm_bt<1>, dim3(NQKV / 128, TOK / 128), dim3(256), 0, stream,
                     xn, WqkvT, (float*)nullptr, (const float*)nullptr,
                     qh, kh, vh, ct, st, TOK, NQKV, DMODEL);
  hipLaunchKernelGGL(attn_kernel, dim3(16, BATCH * HEADS), dim3(256), 0, stream,
                     qh, kh, vh, ao);
  hipLaunchKernelGGL(gemm_bt<2>, dim3(DMODEL / 128, TOK / 128), dim3(256), 0, stream,
                     ao, WoutT, out, bout,
                     (ushort*)nullptr, (ushort*)nullptr, (ushort*)nullptr,
                     (const float*)nullptr, (const float*)nullptr, TOK, DMODEL, DMODEL);
}

// Round 9
// 131.805 us; speedup vs baseline: 1.2045x; 1.0337x over previous
//
#include <hip/hip_runtime.h>
#include <hip/hip_bf16.h>

#define SEQ    2048
#define DMODEL 1024
#define HEADS  16
#define DHEAD  64
#define BATCH  2
#define TOK    (BATCH * SEQ)    // 4096
#define NQKV   (3 * DMODEL)     // 3072
#define QK_SCALE (0.125f * 1.4426950408889634f)   // fold DH^-0.5 and log2(e) into q

typedef __attribute__((ext_vector_type(8))) short bf16x8;
typedef __attribute__((ext_vector_type(4))) float f32x4;

__device__ __forceinline__ float bf2f(ushort u) {
  union { unsigned int i; float f; } v; v.i = ((unsigned int)u) << 16; return v.f;
}
__device__ __forceinline__ ushort f2bf(float f) {
  union { float f; unsigned int i; } v; v.f = f;
  unsigned int r = (v.i + 0x7fffu + ((v.i >> 16) & 1u)) >> 16;
  return (ushort)r;
}

// XOR-swizzle for [row][128-byte-row] LDS tiles (attn): spreads 16B slots across banks.
__device__ __forceinline__ int swz(int row, int byteoff) {
  return row * 128 + (byteoff ^ ((row & 7) << 4));
}
// K-row permutation (attn): LDS slot s = nf*16+g*4+r holds global kv row
// pi(s) = nf1*32 + g*8 + nf0*4 + r  -> lane (g) ends up holding exactly kv
// {g*8..g*8+7} u {32+g*8..+7}: the PV A-fragment, with no cross-lane traffic.
__device__ __forceinline__ int kperm(int s) {
  return (s & 0x20) | ((s & 0x0C) << 1) | ((s & 0x10) >> 2) | (s & 3);
}

#define GLL16(g, l)                                                                     \
  __builtin_amdgcn_global_load_lds((const __attribute__((address_space(1))) void*)(g),  \
                                   (__attribute__((address_space(3))) void*)(l), 16, 0, 0)

// ---------------- LayerNorm: fp32 in -> bf16 out, one block per token ----------------
__global__ __launch_bounds__(256) void ln_kernel(const float* __restrict__ x,
                                                 const float* __restrict__ g,
                                                 const float* __restrict__ b,
                                                 ushort* __restrict__ xn) {
  int t = blockIdx.x;
  int tid = threadIdx.x;
  const float* row = x + (size_t)t * DMODEL;
  float4 v = *(const float4*)(row + tid * 4);
  float s  = v.x + v.y + v.z + v.w;
  float s2 = v.x * v.x + v.y * v.y + v.z * v.z + v.w * v.w;
#pragma unroll
  for (int m = 32; m >= 1; m >>= 1) {
    s  += __shfl_down(s, m);
    s2 += __shfl_down(s2, m);
  }
  __shared__ float ws[4], ws2[4];
  if ((tid & 63) == 0) { ws[tid >> 6] = s; ws2[tid >> 6] = s2; }
  __syncthreads();
  s  = ws[0] + ws[1] + ws[2] + ws[3];
  s2 = ws2[0] + ws2[1] + ws2[2] + ws2[3];
  float mu  = s * (1.f / DMODEL);
  float var = s2 * (1.f / DMODEL) - mu * mu;
  float rs  = rsqrtf(var + 1e-5f);
  float4 gv = *(const float4*)(g + tid * 4);
  float4 bv = *(const float4*)(b + tid * 4);
  ushort4 o;
  o.x = f2bf((v.x - mu) * rs * gv.x + bv.x);
  o.y = f2bf((v.y - mu) * rs * gv.y + bv.y);
  o.z = f2bf((v.z - mu) * rs * gv.z + bv.z);
  o.w = f2bf((v.w - mu) * rs * gv.w + bv.w);
  *(ushort4*)(xn + (size_t)t * DMODEL + tid * 4) = o;
}

// ---------------- fp32 [R][C] -> bf16 [C][R] transpose ----------------
__global__ void transpose_f2b(const float* __restrict__ in, ushort* __restrict__ out,
                              int R, int C) {
  __shared__ float tile[32][33];
  int c0 = blockIdx.x * 32, r0 = blockIdx.y * 32;
  int x = threadIdx.x, y = threadIdx.y;
#pragma unroll
  for (int i = 0; i < 32; i += 8) tile[y + i][x] = in[(size_t)(r0 + y + i) * C + c0 + x];
  __syncthreads();
#pragma unroll
  for (int i = 0; i < 32; i += 8) out[(size_t)(c0 + y + i) * R + r0 + x] = f2bf(tile[x][y + i]);
}

// ---------------- RoPE cos/sin tables [SEQ][DHEAD] fp32 ----------------
__global__ void rope_tab_kernel(float* __restrict__ ct, float* __restrict__ st) {
  int n = blockIdx.x, d = threadIdx.x;
  float invf = expf(-logf(10000.f) * (float)(d & 31) * (1.f / 32.f));
  float a = (float)n * invf;
  ct[n * DHEAD + d] = cosf(a);
  st[n * DHEAD + d] = sinf(a);
}

// ---- GEMM: C[M][N] = A[M][K] * BT[N][K]^T; bf16 in. BK=32, 16KB LDS.
// Round-6 structure (best measured): 2-phase loop, slot-XOR swizzle (conflicts=0).
// LDS (row, slot) holds global (row, slot ^ ((row>>1)&3)); source pre-swizzled
// (gll16 dest linear, rule #21); fragment read XORs the same involution.
// EPI==1: RoPE + head-scatter epilogue (QKV GEMM) -> qh/kh/vh, q pre-scaled for exp2.
// EPI==2: fp32 + bias -> Cf (output projection).
template<int EPI>
__global__ __launch_bounds__(256) void gemm_bt(const ushort* __restrict__ A,
                                               const ushort* __restrict__ BT,
                                               float* __restrict__ Cf,
                                               const float* __restrict__ bias,
                                               ushort* __restrict__ qh,
                                               ushort* __restrict__ kh,
                                               ushort* __restrict__ vh,
                                               const float* __restrict__ ct,
                                               const float* __restrict__ st,
                                               int M, int N, int K) {
  __shared__ __align__(16) ushort As[128 * 32];
  __shared__ __align__(16) ushort Bs[128 * 32];
  int tid = threadIdx.x;
  int w = tid >> 6, lane = tid & 63;
  int lrow = lane & 15, g = lane >> 4;
  int m0 = blockIdx.y * 128, n0 = blockIdx.x * 128;
  int wr = (w >> 1) * 64, wc = (w & 1) * 64;
  // staging: lane covers row (lane>>2) of a 16-row chunk, slot lane&3; source col
  // pre-swizzled with the involution slot ^= (row>>1)&3.
  int grow = lane >> 2;
  int gcol = ((lane & 3) ^ ((grow >> 1) & 3)) * 8;
  ushort* ldsA0 = As + w * 512;
  ushort* ldsA1 = As + 2048 + w * 512;
  ushort* ldsB0 = Bs + w * 512;
  ushort* ldsB1 = Bs + 2048 + w * 512;
  // fragment read: logical slot g lives at LDS slot g ^ ((row>>1)&3); row bits 1,2
  // within a 16-row fragment come from lrow only.
  int fcol = (g ^ ((lrow >> 1) & 3)) * 8;
  f32x4 acc[4][4] = {};
  for (int k0 = 0; k0 < K; k0 += 32) {
    __syncthreads();
    GLL16(A  + (size_t)(m0 + w * 16 + grow) * K + k0 + gcol, ldsA0);
    GLL16(A  + (size_t)(m0 + 64 + w * 16 + grow) * K + k0 + gcol, ldsA1);
    GLL16(BT + (size_t)(n0 + w * 16 + grow) * K + k0 + gcol, ldsB0);
    GLL16(BT + (size_t)(n0 + 64 + w * 16 + grow) * K + k0 + gcol, ldsB1);
    __syncthreads();
    bf16x8 af[4], bfr[4];
#pragma unroll
    for (int i = 0; i < 4; i++) af[i]  = *(const bf16x8*)(As + (wr + i * 16 + lrow) * 32 + fcol);
#pragma unroll
    for (int i = 0; i < 4; i++) bfr[i] = *(const bf16x8*)(Bs + (wc + i * 16 + lrow) * 32 + fcol);
    __builtin_amdgcn_s_setprio(1);
#pragma unroll
    for (int mf = 0; mf < 4; mf++)
#pragma unroll
      for (int nf = 0; nf < 4; nf++)
        acc[mf][nf] = __builtin_amdgcn_mfma_f32_16x16x32_bf16(af[mf], bfr[nf], acc[mf][nf], 0, 0, 0);
    __builtin_amdgcn_s_setprio(0);
  }
#pragma unroll
  for (int mf = 0; mf < 4; mf++)
#pragma unroll
    for (int nf = 0; nf < 4; nf++) {
      int col = n0 + wc + nf * 16 + lrow;
#pragma unroll
      for (int r = 0; r < 4; r++) {
        int rowi = m0 + wr + mf * 16 + g * 4 + r;   // C/D: col=lane&15, row=4*(lane>>4)+reg
        float val = acc[mf][nf][r];
        if (EPI == 2) {
          Cf[(size_t)rowi * N + col] = val + bias[col];
        } else {
          int mat = col >> 10, c1 = col & 1023;
          int h = c1 >> 6, d = c1 & 63;
          int bb = rowi >> 11, n = rowi & (SEQ - 1);
          if (mat < 2) {
            float partner = acc[mf][nf ^ 2][r];     // col ^ 32 lives in the same lane
            float cs = ct[n * DHEAD + d], sn = st[n * DHEAD + d];
            float sgn = (d & 32) ? 1.f : -1.f;
            val = val * cs + sgn * partner * sn;
            if (mat == 0) val *= QK_SCALE;
          }
          ushort* dst = (mat == 0) ? qh : (mat == 1) ? kh : vh;
          dst[((size_t)(bb * HEADS + h) * SEQ + n) * DHEAD + d] = f2bf(val);
        }
      }
    }
}

// ---------------- causal flash attention ----------------
// UN-PAIRED: block = (one 64-row q-tile, head); 1024 blocks = 4/CU (2x TLP vs
// paired). Descending-qt dispatch keeps the triangular tail balanced; heads
// grouped 4-per-XCD for K/V L2 locality. Swapped QK^T (mfma(K,Q)) + kperm'd K
// rows => lane-local softmax, no P round-trip, no shuffles (rd4 mechanism).
__global__ __launch_bounds__(256) void attn_kernel(const ushort* __restrict__ q,
                                                   const ushort* __restrict__ k,
                                                   const ushort* __restrict__ v,
                                                   ushort* __restrict__ ao) {
  int wgid = blockIdx.x + gridDim.x * blockIdx.y;   // 0..1023
  int xcd = wgid & 7, idx = wgid >> 3;
  int bh = xcd * 4 + (idx & 3);          // 4 heads per XCD (K+V 2MB fits L2)
  int qt = 31 - (idx >> 2);              // big q-tiles dispatch first
  int tid = threadIdx.x, w = tid >> 6, lane = tid & 63;
  int lrow = lane & 15, g = lane >> 4;
  __shared__ __align__(16) ushort Ks[2][64 * 64];
  __shared__ __align__(16) ushort Vt[2][64 * 64];
  const ushort* qb = q + (size_t)bh * SEQ * DHEAD;
  const ushort* kb = k + (size_t)bh * SEQ * DHEAD;
  const ushort* vb = v + (size_t)bh * SEQ * DHEAD;
  const ushort* qp = qb + (size_t)(qt * 64 + w * 16 + lrow) * DHEAD + g * 8;
  bf16x8 qf0 = *(const bf16x8*)(qp), qf1 = *(const bf16x8*)(qp + 32);
  f32x4 aO[4] = {};
  float l_s = 0.f;

  int krow = tid >> 2, kco = (tid & 3) * 16;
  int pik = kperm(krow);
  int d0 = (tid & 31) * 2, kv8 = (tid >> 5) * 8;
  int4 ka0, ka1;
  unsigned int vd[8];

#define STAGE_ISSUE(j)                                                          \
  {                                                                             \
    const ushort* ks = kb + ((size_t)((j) * 64 + pik)) * DHEAD + kco;           \
    ka0 = *(const int4*)ks;                                                     \
    ka1 = *(const int4*)(ks + 8);                                               \
    const ushort* vs = vb + ((size_t)((j) * 64 + kv8)) * DHEAD + d0;            \
    _Pragma("unroll")                                                           \
    for (int jj = 0; jj < 8; jj++) vd[jj] = *(const unsigned int*)(vs + jj * DHEAD); \
  }

#define STAGE_WRITE(bsel)                                                       \
  {                                                                             \
    char* kd = (char*)Ks[bsel];                                                 \
    *(int4*)(kd + swz(krow, (tid & 3) * 32)) = ka0;                             \
    *(int4*)(kd + swz(krow, (tid & 3) * 32 + 16)) = ka1;                        \
    unsigned int lo[4], hi[4];                                                  \
    _Pragma("unroll")                                                           \
    for (int jj = 0; jj < 4; jj++) {                                            \
      lo[jj] = __builtin_amdgcn_perm(vd[2 * jj + 1], vd[2 * jj], 0x05040100u);  \
      hi[jj] = __builtin_amdgcn_perm(vd[2 * jj + 1], vd[2 * jj], 0x07060302u);  \
    }                                                                           \
    char* vdst = (char*)Vt[bsel];                                               \
    *(int4*)(vdst + swz(d0, kv8 * 2))     = *(int4*)lo;                         \
    *(int4*)(vdst + swz(d0 + 1, kv8 * 2)) = *(int4*)hi;                         \
  }

  STAGE_ISSUE(0);
  STAGE_WRITE(0);
  __syncthreads();
  int cur = 0;

  for (int jt = 0; jt <= qt; jt++) {
    if (jt < qt) STAGE_ISSUE(jt + 1);
    const char* kbuf = (const char*)Ks[cur];
    const char* vbuf = (const char*)Vt[cur];
    bf16x8 kf[8];
#pragma unroll
    for (int nf = 0; nf < 4; nf++) {
      kf[2 * nf]     = *(const bf16x8*)(kbuf + swz(nf * 16 + lrow, g * 16));
      kf[2 * nf + 1] = *(const bf16x8*)(kbuf + swz(nf * 16 + lrow, g * 16 + 64));
    }
    // S^T = K.Q^T ; scores for q-row (w*16+lrow) land lane-local
    bf16x8 pa0, pa1;
    {
      f32x4 aS[4] = {};
      __builtin_amdgcn_s_setprio(1);
#pragma unroll
      for (int nf = 0; nf < 4; nf++) {
        aS[nf] = __builtin_amdgcn_mfma_f32_16x16x32_bf16(kf[2 * nf], qf0, aS[nf], 0, 0, 0);
        aS[nf] = __builtin_amdgcn_mfma_f32_16x16x32_bf16(kf[2 * nf + 1], qf1, aS[nf], 0, 0, 0);
      }
      __builtin_amdgcn_s_setprio(0);
      union { bf16x8 v; __hip_bfloat162 h[4]; } a0, a1;
      bool diag = (jt == qt);
#pragma unroll
      for (int nf = 0; nf < 4; nf++) {
        float p[4];
#pragma unroll
        for (int r = 0; r < 4; r++) {
          int kvl = (nf >> 1) * 32 + g * 8 + (nf & 1) * 4 + r;
          p[r] = exp2f(aS[nf][r]);
          if (diag && kvl > w * 16 + lrow) p[r] = 0.f;
          l_s += p[r];
        }
        __hip_bfloat162 plo = __float22bfloat162_rn({p[0], p[1]});
        __hip_bfloat162 phi = __float22bfloat162_rn({p[2], p[3]});
        if (nf < 2) { a0.h[(nf & 1) * 2] = plo; a0.h[(nf & 1) * 2 + 1] = phi; }
        else        { a1.h[(nf & 1) * 2] = plo; a1.h[(nf & 1) * 2 + 1] = phi; }
      }
      pa0 = a0.v; pa1 = a1.v;
    }
    bf16x8 vf[8];
#pragma unroll
    for (int nf = 0; nf < 4; nf++) {
      vf[2 * nf]     = *(const bf16x8*)(vbuf + swz(nf * 16 + lrow, g * 16));
      vf[2 * nf + 1] = *(const bf16x8*)(vbuf + swz(nf * 16 + lrow, g * 16 + 64));
    }
    __builtin_amdgcn_s_setprio(1);
#pragma unroll
    for (int nf = 0; nf < 4; nf++) {
      aO[nf] = __builtin_amdgcn_mfma_f32_16x16x32_bf16(pa0, vf[2 * nf], aO[nf], 0, 0, 0);
      aO[nf] = __builtin_amdgcn_mfma_f32_16x16x32_bf16(pa1, vf[2 * nf + 1], aO[nf], 0, 0, 0);
    }
    __builtin_amdgcn_s_setprio(0);
    if (jt < qt) STAGE_WRITE(cur ^ 1);
    __syncthreads();
    cur ^= 1;
  }

  // denominator: sum across the 4 lanes (g) sharing each q-row, then write out
  l_s += __shfl_xor(l_s, 16);
  l_s += __shfl_xor(l_s, 32);
  int b = bh >> 4, h = bh & 15;
#pragma unroll
  for (int r = 0; r < 4; r++) {
    float inv = 1.f / __shfl(l_s, g * 4 + r);
#pragma unroll
    for (int nf = 0; nf < 4; nf++) {
      int col = h * DHEAD + nf * 16 + lrow;
      int tok = b * SEQ + qt * 64 + w * 16 + g * 4 + r;
      ao[(size_t)tok * DMODEL + col] = f2bf(aO[nf][r] * inv);
    }
  }
#undef STAGE_ISSUE
#undef STAGE_WRITE
}

extern "C" void kernel_launch(void* const* d_in, const int* in_sizes, int n_in,
                              void* d_out, int out_size, void* d_ws, size_t ws_size,
                              hipStream_t stream) {
  const float* x    = (const float*)d_in[0];
  const float* Wqkv = (const float*)d_in[1];
  const float* Wout = (const float*)d_in[2];
  const float* bout = (const float*)d_in[3];
  const float* lng  = (const float*)d_in[4];
  const float* lnb  = (const float*)d_in[5];
  float* out = (float*)d_out;

  ushort* xn    = (ushort*)d_ws;                       // reused as ao after QKV GEMM
  ushort* WqkvT = xn + (size_t)TOK * DMODEL;
  ushort* WoutT = WqkvT + (size_t)NQKV * DMODEL;
  ushort* qh    = WoutT + (size_t)DMODEL * DMODEL;
  ushort* kh    = qh + (size_t)BATCH * HEADS * SEQ * DHEAD;
  ushort* vh    = kh + (size_t)BATCH * HEADS * SEQ * DHEAD;
  float*  ct    = (float*)(vh + (size_t)BATCH * HEADS * SEQ * DHEAD);
  float*  st    = ct + SEQ * DHEAD;
  ushort* ao    = xn;

  hipLaunchKernelGGL(ln_kernel, dim3(TOK), dim3(256), 0, stream, x, lng, lnb, xn);
  hipLaunchKernelGGL(transpose_f2b, dim3(NQKV / 32, DMODEL / 32), dim3(32, 8), 0, stream,
                     Wqkv, WqkvT, DMODEL, NQKV);
  hipLaunchKernelGGL(transpose_f2b, dim3(DMODEL / 32, DMODEL / 32), dim3(32, 8), 0, stream,
                     Wout, WoutT, DMODEL, DMODEL);
  hipLaunchKernelGGL(rope_tab_kernel, dim3(SEQ), dim3(DHEAD), 0, stream, ct, st);
  hipLaunchKernelGGL(gemm_bt<1>, dim3(NQKV / 128, TOK / 128), dim3(256), 0, stream,
                     xn, WqkvT, (float*)nullptr, (const float*)nullptr,
                     qh, kh, vh, ct, st, TOK, NQKV, DMODEL);
  hipLaunchKernelGGL(attn_kernel, dim3(32, 32), dim3(256), 0, stream,
                     qh, kh, vh, ao);
  hipLaunchKernelGGL(gemm_bt<2>, dim3(DMODEL / 128, TOK / 128), dim3(256), 0, stream,
                     ao, WoutT, out, bout,
                     (ushort*)nullptr, (ushort*)nullptr, (ushort*)nullptr,
                     (const float*)nullptr, (const float*)nullptr, TOK, DMODEL, DMODEL);
}